// Round 9
// baseline (884.061 us; speedup 1.0000x reference)
//
#include <hip/hip_runtime.h>
#include <cstdint>
#include <cstddef>

#define HD 128

typedef __attribute__((ext_vector_type(8))) short bf16x8;
typedef __attribute__((ext_vector_type(8))) unsigned short u16x8;
typedef __attribute__((ext_vector_type(4))) float f32x4;

__device__ __forceinline__ unsigned short f2bf(float x) {
    unsigned int b = __float_as_uint(x);
    b += 0x7FFFu + ((b >> 16) & 1u);
    return (unsigned short)(b >> 16);
}
__device__ __forceinline__ float bf2f(unsigned short u) {
    return __uint_as_float(((unsigned int)u) << 16);
}

// ---------------- edge-index handling ----------------
// flag=1 -> int32 data, flag=0 -> int64
__global__ void detect_kernel(const unsigned* __restrict__ w, int* __restrict__ flag) {
    if (threadIdx.x == 0) *flag = 0;
    __syncthreads();
    unsigned v = w[2 * threadIdx.x + 1];
    if (v != 0u) atomicOr(flag, 1);
}

__device__ __forceinline__ int eload(const void* raw, int is32, size_t i) {
    return is32 ? ((const int*)raw)[i] : (int)((const long long*)raw)[i];
}

// ---------------- CSR build: two-level bucket sort (bin = dst>>9) ----------------
#define EPB 4096

__global__ __launch_bounds__(256) void p1_count(const void* __restrict__ raw,
                                                const int* __restrict__ flag, int E,
                                                int* __restrict__ tot, int nbins) {
    __shared__ int h[256];
    const int tid = threadIdx.x;
    const int is32 = *flag;
    h[tid] = 0;
    __syncthreads();
    const int base = blockIdx.x * EPB;
    const int lim = min(E, base + EPB);
    for (int i = base + tid; i < lim; i += 256) atomicAdd(&h[eload(raw, is32, (size_t)E + i) >> 9], 1);
    __syncthreads();
    if (tid < nbins && h[tid]) atomicAdd(&tot[tid], h[tid]);
}

__global__ __launch_bounds__(256) void p1_scan(const int* __restrict__ tot,
                                               int* __restrict__ base, int* __restrict__ cursor,
                                               int* __restrict__ rowptr, int nbins, int n, int E) {
    __shared__ int s[256];
    const int tid = threadIdx.x;
    const int v = (tid < nbins) ? tot[tid] : 0;
    s[tid] = v;
    __syncthreads();
#pragma unroll
    for (int o = 1; o < 256; o <<= 1) {
        int t = (tid >= o) ? s[tid - o] : 0;
        __syncthreads();
        s[tid] += t;
        __syncthreads();
    }
    if (tid < nbins) {
        base[tid] = s[tid] - v;
        cursor[tid] = s[tid] - v;
    }
    if (tid == 0) {
        base[nbins] = E;
        rowptr[n] = E;
    }
}

__global__ __launch_bounds__(256) void p1_scatter(const void* __restrict__ raw,
                                                  const int* __restrict__ flag, int E,
                                                  int* __restrict__ cursor,
                                                  int* __restrict__ ssrc, int* __restrict__ sdst) {
    __shared__ int h[256];
    __shared__ int cur[256];
    const int tid = threadIdx.x;
    const int is32 = *flag;
    h[tid] = 0;
    __syncthreads();
    const int base = blockIdx.x * EPB;
    const int lim = min(E, base + EPB);
    for (int i = base + tid; i < lim; i += 256) atomicAdd(&h[eload(raw, is32, (size_t)E + i) >> 9], 1);
    __syncthreads();
    if (h[tid]) cur[tid] = atomicAdd(&cursor[tid], h[tid]);
    __syncthreads();
    for (int i = base + tid; i < lim; i += 256) {
        const int d = eload(raw, is32, (size_t)E + i);
        const int pos = atomicAdd(&cur[d >> 9], 1);
        sdst[pos] = d;
        ssrc[pos] = eload(raw, is32, i);
    }
}

__global__ __launch_bounds__(256) void p2_build(const int* __restrict__ sdst,
                                                const int* __restrict__ ssrc,
                                                const int* __restrict__ bucket_base,
                                                int* __restrict__ rowptr, int* __restrict__ csr,
                                                int n) {
    const int bin = blockIdx.x;
    const int b0 = bucket_base[bin], b1 = bucket_base[bin + 1];
    __shared__ int cnt[512];
    __shared__ int ps[256];
    __shared__ int cur[512];
    const int tid = threadIdx.x;
    cnt[tid] = 0;
    cnt[tid + 256] = 0;
    __syncthreads();
    for (int e = b0 + tid; e < b1; e += 256) atomicAdd(&cnt[sdst[e] & 511], 1);
    __syncthreads();
    const int a = cnt[2 * tid], b = cnt[2 * tid + 1];
    ps[tid] = a + b;
    __syncthreads();
#pragma unroll
    for (int o = 1; o < 256; o <<= 1) {
        int t = (tid >= o) ? ps[tid - o] : 0;
        __syncthreads();
        ps[tid] += t;
        __syncthreads();
    }
    const int e0 = ps[tid] - (a + b);
    const int e1 = e0 + a;
    const int v0 = bin * 512 + 2 * tid;
    if (v0 < n) rowptr[v0] = b0 + e0;
    if (v0 + 1 < n) rowptr[v0 + 1] = b0 + e1;
    cur[2 * tid] = b0 + e0;
    cur[2 * tid + 1] = b0 + e1;
    __syncthreads();
    for (int e = b0 + tid; e < b1; e += 256) {
        const int pos = atomicAdd(&cur[sdst[e] & 511], 1);
        csr[pos] = ssrc[e];
    }
}

// ---------------- all-weights transpose+convert ----------------
// wt mat index m: 0 = Wn; m=1..16: j=m-1, grp=j>>2, pos=j&3 ->
//   pos 0/1/2 = WQ/WK/WV[grp], pos 3 = WO[grp]; m=17 = Wout.
// A uses wt[0..3]=Wn,Q0,K0,V0; B_l uses wt[4+4l..7+4l]=WO_l,Q_{l+1},K_{l+1},V_{l+1};
// C uses wt[16..17]=WO3,Wout.   wt[m][c][k] = W_m[k][c] in bf16.
struct WPtrs { const float* p[6]; };

__global__ void wtrans_all(WPtrs ws, unsigned short* __restrict__ dst) {
    int i = blockIdx.x * 256 + threadIdx.x;  // over 18*16384
    if (i >= 18 * 16384) return;
    int m = i >> 14;
    int r = i & 16383;
    int k = r >> 7, c = r & 127;
    const float* s;
    int off;
    if (m == 0)      { s = ws.p[0]; off = 0; }
    else if (m < 17) {
        int j = m - 1, grp = j >> 2, pos = j & 3;
        off = grp;
        s = (pos == 0) ? ws.p[1] : (pos == 1) ? ws.p[2] : (pos == 2) ? ws.p[3] : ws.p[4];
    } else           { s = ws.p[5]; off = 0; }
    dst[(size_t)m * 16384 + (size_t)c * HD + k] = f2bf(s[(size_t)off * 16384 + r]);
}

// ---------------- fused MFMA linear chain (register-pipelined weight staging) --------
// Block = 256 threads = 4 waves, 64 rows; wave w owns rows [blk*64 + w*16, +16).
// MODE 0 (A):  h = x@Wn+bn            -> hb, then Q/K/V (layer 0)
// MODE 1 (B):  h = LN(hb+mb@WO+bO)    -> hb, then Q/K/V (layer l+1)
// MODE 2 (C):  h = LN(hb+mb@WO+bO)    -> out = h@Wout+bout (fp32)
// While mat m's MFMA runs, mat m+1's weights are in flight global->regs (T14).
#define WLSTRIDE 132

__device__ __forceinline__ void load_w_regs(const unsigned short* __restrict__ Wt,
                                            u16x8* wr, int tid) {
#pragma unroll
    for (int s = 0; s < 8; ++s) {
        const int slot = s * 256 + tid;
        const int row = slot >> 4, c8 = (slot & 15) << 3;
        wr[s] = *(const u16x8*)&Wt[(size_t)row * HD + c8];
    }
}
__device__ __forceinline__ void write_w_lds(const u16x8* wr, unsigned short* __restrict__ wl,
                                            int tid) {
#pragma unroll
    for (int s = 0; s < 8; ++s) {
        const int slot = s * 256 + tid;
        const int row = slot >> 4, c8 = (slot & 15) << 3;
        *(u16x8*)&wl[row * WLSTRIDE + c8] = wr[s];
    }
}

__device__ __forceinline__ bf16x8 load_a_bf(const unsigned short* Xb, int row, int k, int n) {
    bf16x8 a = (bf16x8){0, 0, 0, 0, 0, 0, 0, 0};
    if (row < n) a = *(const bf16x8*)&Xb[(size_t)row * HD + k];
    return a;
}
__device__ __forceinline__ bf16x8 load_a_f32(const float* Xf, int row, int k, int n) {
    bf16x8 a = (bf16x8){0, 0, 0, 0, 0, 0, 0, 0};
    if (row < n) {
        float4 x0 = *(const float4*)&Xf[(size_t)row * HD + k];
        float4 x1 = *(const float4*)&Xf[(size_t)row * HD + k + 4];
        a[0] = (short)f2bf(x0.x); a[1] = (short)f2bf(x0.y);
        a[2] = (short)f2bf(x0.z); a[3] = (short)f2bf(x0.w);
        a[4] = (short)f2bf(x1.x); a[5] = (short)f2bf(x1.y);
        a[6] = (short)f2bf(x1.z); a[7] = (short)f2bf(x1.w);
    }
    return a;
}

template <int MODE>
__global__ __launch_bounds__(256) void fused_k(
    const void* __restrict__ Xin, const unsigned short* __restrict__ W,
    const float* __restrict__ bias0,
    const float* __restrict__ lng, const float* __restrict__ lnb,
    unsigned short* __restrict__ hb,
    const float* __restrict__ b1, const float* __restrict__ b2, const float* __restrict__ b3,
    unsigned short* __restrict__ Qb, unsigned short* __restrict__ KV,
    float* __restrict__ Yout, int n) {
    __shared__ unsigned short wl[128 * WLSTRIDE];
    __shared__ unsigned short hl[64 * WLSTRIDE];
    const int tid = threadIdx.x;
    const int w = tid >> 6;
    const int lane = tid & 63;
    const int t = lane & 15, g = lane >> 4;
    const int waveBase = blockIdx.x * 64 + w * 16;

    // ---- GEMM0: W0 regs -> LDS; A-frags from Xin overlap ----
    u16x8 wreg[8];
    load_w_regs(W, wreg, tid);
    bf16x8 af[4];
#pragma unroll
    for (int ks = 0; ks < 4; ++ks) {
        const int k = ks * 32 + g * 8;
        af[ks] = (MODE == 0) ? load_a_f32((const float*)Xin, waveBase + t, k, n)
                             : load_a_bf((const unsigned short*)Xin, waveBase + t, k, n);
    }
    write_w_lds(wreg, wl, tid);
    __syncthreads();

    // prefetch W1 while GEMM0 computes
    load_w_regs(W + 16384, wreg, tid);

    f32x4 acc[8];
#pragma unroll
    for (int nf = 0; nf < 8; ++nf) acc[nf] = (f32x4){0.f, 0.f, 0.f, 0.f};
#pragma unroll
    for (int ks = 0; ks < 4; ++ks) {
        const int k = ks * 32 + g * 8;
#pragma unroll
        for (int nf = 0; nf < 8; ++nf) {
            bf16x8 b = *(const bf16x8*)&wl[(nf * 16 + t) * WLSTRIDE + k];
            acc[nf] = __builtin_amdgcn_mfma_f32_16x16x32_bf16(af[ks], b, acc[nf], 0, 0, 0);
        }
    }

    // ---- epilogue 0: bias (+resid+LN), write hb + hl ----
    float v[8][4];
#pragma unroll
    for (int nf = 0; nf < 8; ++nf) {
        const int col = nf * 16 + t;
        const float bv = bias0[col];
#pragma unroll
        for (int r = 0; r < 4; ++r) {
            float x = acc[nf][r] + bv;
            if (MODE >= 1) {
                const int row = waveBase + g * 4 + r;
                if (row < n) x += bf2f(hb[(size_t)row * HD + col]);
            }
            v[nf][r] = x;
        }
    }
    if (MODE >= 1) {
#pragma unroll
        for (int r = 0; r < 4; ++r) {
            float s = 0.f, sq = 0.f;
#pragma unroll
            for (int nf = 0; nf < 8; ++nf) { s += v[nf][r]; sq += v[nf][r] * v[nf][r]; }
#pragma unroll
            for (int mask = 1; mask < 16; mask <<= 1) {
                s += __shfl_xor(s, mask, 64);
                sq += __shfl_xor(sq, mask, 64);
            }
            const float mu = s * (1.f / 128.f);
            const float var = sq * (1.f / 128.f) - mu * mu;
            const float inv = rsqrtf(var + 1e-5f);
#pragma unroll
            for (int nf = 0; nf < 8; ++nf) {
                const int col = nf * 16 + t;
                v[nf][r] = (v[nf][r] - mu) * inv * lng[col] + lnb[col];
            }
        }
    }
#pragma unroll
    for (int r = 0; r < 4; ++r) {
        const int row = waveBase + g * 4 + r;
        const int lrow = w * 16 + g * 4 + r;
        const bool ok = row < n;
#pragma unroll
        for (int nf = 0; nf < 8; ++nf) {
            const int col = nf * 16 + t;
            const unsigned short hv = f2bf(v[nf][r]);
            hl[lrow * WLSTRIDE + col] = hv;
            if (MODE <= 1 && ok) hb[(size_t)row * HD + col] = hv;
        }
    }
    __syncthreads();  // hl visible; all wl reads of GEMM0 done

    // ---- A-frags for downstream GEMMs from hl (read once) ----
    bf16x8 hf[4];
#pragma unroll
    for (int ks = 0; ks < 4; ++ks)
        hf[ks] = *(const bf16x8*)&hl[(w * 16 + t) * WLSTRIDE + ks * 32 + g * 8];

    const int NM = (MODE == 2) ? 1 : 3;
    const float* bs[3] = {b1, b2, b3};
#pragma unroll
    for (int mat = 1; mat <= NM; ++mat) {
        write_w_lds(wreg, wl, tid);  // W_mat regs -> LDS
        __syncthreads();
        if (mat < NM) load_w_regs(W + (size_t)(mat + 1) * 16384, wreg, tid);  // prefetch next

        f32x4 a2[8];
#pragma unroll
        for (int nf = 0; nf < 8; ++nf) a2[nf] = (f32x4){0.f, 0.f, 0.f, 0.f};
#pragma unroll
        for (int ks = 0; ks < 4; ++ks) {
            const int k = ks * 32 + g * 8;
#pragma unroll
            for (int nf = 0; nf < 8; ++nf) {
                bf16x8 b = *(const bf16x8*)&wl[(nf * 16 + t) * WLSTRIDE + k];
                a2[nf] = __builtin_amdgcn_mfma_f32_16x16x32_bf16(hf[ks], b, a2[nf], 0, 0, 0);
            }
        }
        if (MODE == 2) {
#pragma unroll
            for (int r = 0; r < 4; ++r) {
                const int row = waveBase + g * 4 + r;
                if (row < n) {
#pragma unroll
                    for (int nf = 0; nf < 8; ++nf) {
                        const int col = nf * 16 + t;
                        Yout[(size_t)row * HD + col] = a2[nf][r] + b1[col];
                    }
                }
            }
        } else {
            unsigned short* outp = (mat == 1) ? Qb : KV;
            const int rs = (mat == 1) ? 128 : 256;
            const int co = (mat == 3) ? 128 : 0;
            const float* bb = bs[mat - 1];
#pragma unroll
            for (int r = 0; r < 4; ++r) {
                const int row = waveBase + g * 4 + r;
                if (row < n) {
#pragma unroll
                    for (int nf = 0; nf < 8; ++nf) {
                        const int col = nf * 16 + t;
                        outp[(size_t)row * rs + co + col] = f2bf(a2[nf][r] + bb[col]);
                    }
                }
            }
        }
        if (mat < NM) __syncthreads();  // wl reads done before next write
    }
}

// ---------------- fused edge attention: no-max softmax, bf16 KV, 8-edge ILP ----------------
__global__ __launch_bounds__(256) void attn_kernel(
    const unsigned short* __restrict__ Qb, const unsigned short* __restrict__ KV,
    const int* __restrict__ rowptr, const int* __restrict__ csr,
    unsigned short* __restrict__ Mb, int n) {
    const int d = (blockIdx.x * 256 + threadIdx.x) >> 6;
    if (d >= n) return;
    const int lane = threadIdx.x & 63;
    const int t = lane & 7, g = lane >> 3;
    const int beg = rowptr[d], end = rowptr[d + 1];

    const float scale = 0.08838834764831845f;  // 1/sqrt(128)
    float qv[16];
    {
        u16x8 q0 = *(const u16x8*)&Qb[(size_t)d * HD + t * 16];
        u16x8 q1 = *(const u16x8*)&Qb[(size_t)d * HD + t * 16 + 8];
#pragma unroll
        for (int j = 0; j < 8; ++j) {
            qv[j] = bf2f(q0[j]) * scale;
            qv[8 + j] = bf2f(q1[j]) * scale;
        }
    }
    float ss = 0.f;
    float acc[16];
#pragma unroll
    for (int j = 0; j < 16; ++j) acc[j] = 0.f;

    const int nit = (end - beg + 7) >> 3;
    for (int it = 0; it < nit; ++it) {
        const int idx = beg + it * 8 + g;
        const bool act = idx < end;
        const int s = act ? csr[idx] : 0;
        const unsigned short* kvp = &KV[(size_t)s * 256 + t * 16];
        const u16x8 k0 = *(const u16x8*)kvp;
        const u16x8 k1 = *(const u16x8*)(kvp + 8);
        const u16x8 v0 = *(const u16x8*)(kvp + 128);
        const u16x8 v1 = *(const u16x8*)(kvp + 136);
        float p = 0.f;
#pragma unroll
        for (int j = 0; j < 8; ++j) {
            p = fmaf(bf2f(k0[j]), qv[j], p);
            p = fmaf(bf2f(k1[j]), qv[8 + j], p);
        }
#pragma unroll
        for (int mask = 1; mask < 8; mask <<= 1) p += __shfl_xor(p, mask, 64);
        const float e = act ? __expf(p) : 0.f;  // LN-scale scores: no max-sub needed in fp32
        ss += e;
#pragma unroll
        for (int j = 0; j < 8; ++j) {
            acc[j] = fmaf(e, bf2f(v0[j]), acc[j]);
            acc[8 + j] = fmaf(e, bf2f(v1[j]), acc[8 + j]);
        }
    }

#pragma unroll
    for (int mask = 8; mask <= 32; mask <<= 1) {
        ss += __shfl_xor(ss, mask, 64);
#pragma unroll
        for (int j = 0; j < 16; ++j) acc[j] += __shfl_xor(acc[j], mask, 64);
    }

    const float inv = (end > beg) ? 1.f / ss : 0.f;
    if (g == 0) {
        u16x8 o0, o1;
#pragma unroll
        for (int j = 0; j < 8; ++j) {
            o0[j] = f2bf(acc[j] * inv);
            o1[j] = f2bf(acc[8 + j] * inv);
        }
        *(u16x8*)&Mb[(size_t)d * HD + t * 16] = o0;
        *(u16x8*)&Mb[(size_t)d * HD + t * 16 + 8] = o1;
    }
}

// ---------------- launch ----------------
extern "C" void kernel_launch(void* const* d_in, const int* in_sizes, int n_in,
                              void* d_out, int out_size, void* d_ws, size_t ws_size,
                              hipStream_t stream) {
    const float* x    = (const float*)d_in[0];
    const void*  eix  = d_in[1];
    const float* Wn   = (const float*)d_in[2];
    const float* bn   = (const float*)d_in[3];
    const float* WQ   = (const float*)d_in[4];
    const float* bQ   = (const float*)d_in[5];
    const float* WK   = (const float*)d_in[6];
    const float* bK   = (const float*)d_in[7];
    const float* WV   = (const float*)d_in[8];
    const float* bV   = (const float*)d_in[9];
    const float* WO   = (const float*)d_in[10];
    const float* bO   = (const float*)d_in[11];
    const float* lng  = (const float*)d_in[12];
    const float* lnb  = (const float*)d_in[13];
    const float* Wout = (const float*)d_in[14];
    const float* bout = (const float*)d_in[15];

    const int n = in_sizes[0] / HD;
    const int E = in_sizes[1] / 2;
    const int NBINS = (n + 511) >> 9;

    char* p = (char*)d_ws;
    auto alloc = [&](size_t bytes) -> void* {
        void* r = (void*)p;
        p += (bytes + 255) & ~(size_t)255;
        return r;
    };
    unsigned short* hb = (unsigned short*)alloc((size_t)n * HD * 2);
    unsigned short* qb = (unsigned short*)alloc((size_t)n * HD * 2);
    unsigned short* kv = (unsigned short*)alloc((size_t)n * HD * 4);  // interleaved K|V
    unsigned short* mb = (unsigned short*)alloc((size_t)n * HD * 2);
    int* ssrc   = (int*)alloc((size_t)E * 4);
    int* sdst   = (int*)alloc((size_t)E * 4);
    int* csr    = (int*)alloc((size_t)E * 4);
    int* rowptr = (int*)alloc((size_t)(n + 1) * 4);
    int* btot   = (int*)alloc(256 * 4);
    int* bbase  = (int*)alloc(257 * 4);
    int* bcur   = (int*)alloc(256 * 4);
    int* flag   = (int*)alloc(256);
    unsigned short* wt = (unsigned short*)alloc(18 * 16384 * 2);

    const int EB = (E + EPB - 1) / EPB;
    const int nw = (n + 3) / 4;      // attn: wave per dst
    const int nl = (n + 63) / 64;    // fused linear tiles (64 rows)

    detect_kernel<<<1, 256, 0, stream>>>((const unsigned*)eix, flag);
    hipMemsetAsync(btot, 0, 256 * 4, stream);
    p1_count<<<EB, 256, 0, stream>>>(eix, flag, E, btot, NBINS);
    p1_scan<<<1, 256, 0, stream>>>(btot, bbase, bcur, rowptr, NBINS, n, E);
    p1_scatter<<<EB, 256, 0, stream>>>(eix, flag, E, bcur, ssrc, sdst);
    p2_build<<<NBINS, 256, 0, stream>>>(sdst, ssrc, bbase, rowptr, csr, n);

    WPtrs wp;
    wp.p[0] = Wn; wp.p[1] = WQ; wp.p[2] = WK; wp.p[3] = WV; wp.p[4] = WO; wp.p[5] = Wout;
    wtrans_all<<<(18 * 16384 + 255) / 256, 256, 0, stream>>>(wp, wt);

    // A: h = x@Wn+bn -> hb, then Q/K/V layer 0
    fused_k<0><<<nl, 256, 0, stream>>>(
        x, wt, bn, nullptr, nullptr, hb,
        bQ, bK, bV, qb, kv, nullptr, n);

    for (int l = 0; l < 4; ++l) {
        attn_kernel<<<nw, 256, 0, stream>>>(qb, kv, rowptr, csr, mb, n);
        if (l < 3) {
            // B: h = LN(hb + mb@WO_l + bO_l) -> hb, then Q/K/V layer l+1
            fused_k<1><<<nl, 256, 0, stream>>>(
                mb, wt + (size_t)(4 + 4 * l) * 16384, bO + l * HD, lng + l * HD, lnb + l * HD, hb,
                bQ + (l + 1) * HD, bK + (l + 1) * HD, bV + (l + 1) * HD, qb, kv, nullptr, n);
        } else {
            // C: h = LN(hb + mb@WO_3 + bO_3), out = h@Wout + bout
            fused_k<2><<<nl, 256, 0, stream>>>(
                mb, wt + (size_t)16 * 16384, bO + 3 * HD, lng + 3 * HD, lnb + 3 * HD, hb,
                bout, nullptr, nullptr, nullptr, nullptr, (float*)d_out, n);
        }
    }
}

// Round 10
// 835.796 us; speedup vs baseline: 1.0577x; 1.0577x over previous
//
#include <hip/hip_runtime.h>
#include <cstdint>
#include <cstddef>

#define HD 128

typedef __attribute__((ext_vector_type(8))) short bf16x8;
typedef __attribute__((ext_vector_type(8))) unsigned short u16x8;
typedef __attribute__((ext_vector_type(4))) float f32x4;

__device__ __forceinline__ unsigned short f2bf(float x) {
    unsigned int b = __float_as_uint(x);
    b += 0x7FFFu + ((b >> 16) & 1u);
    return (unsigned short)(b >> 16);
}
__device__ __forceinline__ float bf2f(unsigned short u) {
    return __uint_as_float(((unsigned int)u) << 16);
}

// ---------------- edge-index handling ----------------
// flag=1 -> int32 data, flag=0 -> int64
__global__ void detect_kernel(const unsigned* __restrict__ w, int* __restrict__ flag) {
    if (threadIdx.x == 0) *flag = 0;
    __syncthreads();
    unsigned v = w[2 * threadIdx.x + 1];
    if (v != 0u) atomicOr(flag, 1);
}

__device__ __forceinline__ int eload(const void* raw, int is32, size_t i) {
    return is32 ? ((const int*)raw)[i] : (int)((const long long*)raw)[i];
}

// ---------------- CSR build: two-level bucket sort (bin = dst>>9) ----------------
#define EPB 4096

__global__ __launch_bounds__(256) void p1_count(const void* __restrict__ raw,
                                                const int* __restrict__ flag, int E,
                                                int* __restrict__ tot, int nbins) {
    __shared__ int h[256];
    const int tid = threadIdx.x;
    const int is32 = *flag;
    h[tid] = 0;
    __syncthreads();
    const int base = blockIdx.x * EPB;
    const int lim = min(E, base + EPB);
    for (int i = base + tid; i < lim; i += 256) atomicAdd(&h[eload(raw, is32, (size_t)E + i) >> 9], 1);
    __syncthreads();
    if (tid < nbins && h[tid]) atomicAdd(&tot[tid], h[tid]);
}

__global__ __launch_bounds__(256) void p1_scan(const int* __restrict__ tot,
                                               int* __restrict__ base, int* __restrict__ cursor,
                                               int* __restrict__ rowptr, int nbins, int n, int E) {
    __shared__ int s[256];
    const int tid = threadIdx.x;
    const int v = (tid < nbins) ? tot[tid] : 0;
    s[tid] = v;
    __syncthreads();
#pragma unroll
    for (int o = 1; o < 256; o <<= 1) {
        int t = (tid >= o) ? s[tid - o] : 0;
        __syncthreads();
        s[tid] += t;
        __syncthreads();
    }
    if (tid < nbins) {
        base[tid] = s[tid] - v;
        cursor[tid] = s[tid] - v;
    }
    if (tid == 0) {
        base[nbins] = E;
        rowptr[n] = E;
    }
}

// pack: (src << 9) | (dst & 511)  -- p2 only needs dst's low 9 bits; src < 2^23
__global__ __launch_bounds__(256) void p1_scatter(const void* __restrict__ raw,
                                                  const int* __restrict__ flag, int E,
                                                  int* __restrict__ cursor,
                                                  unsigned* __restrict__ spack) {
    __shared__ int h[256];
    __shared__ int cur[256];
    const int tid = threadIdx.x;
    const int is32 = *flag;
    h[tid] = 0;
    __syncthreads();
    const int base = blockIdx.x * EPB;
    const int lim = min(E, base + EPB);
    for (int i = base + tid; i < lim; i += 256) atomicAdd(&h[eload(raw, is32, (size_t)E + i) >> 9], 1);
    __syncthreads();
    if (h[tid]) cur[tid] = atomicAdd(&cursor[tid], h[tid]);
    __syncthreads();
    for (int i = base + tid; i < lim; i += 256) {
        const int d = eload(raw, is32, (size_t)E + i);
        const int pos = atomicAdd(&cur[d >> 9], 1);
        spack[pos] = ((unsigned)eload(raw, is32, i) << 9) | (unsigned)(d & 511);
    }
}

__global__ __launch_bounds__(256) void p2_build(const unsigned* __restrict__ spack,
                                                const int* __restrict__ bucket_base,
                                                int* __restrict__ rowptr, int* __restrict__ csr,
                                                int n) {
    const int bin = blockIdx.x;
    const int b0 = bucket_base[bin], b1 = bucket_base[bin + 1];
    __shared__ int cnt[512];
    __shared__ int ps[256];
    __shared__ int cur[512];
    const int tid = threadIdx.x;
    cnt[tid] = 0;
    cnt[tid + 256] = 0;
    __syncthreads();
    for (int e = b0 + tid; e < b1; e += 256) atomicAdd(&cnt[spack[e] & 511u], 1);
    __syncthreads();
    const int a = cnt[2 * tid], b = cnt[2 * tid + 1];
    ps[tid] = a + b;
    __syncthreads();
#pragma unroll
    for (int o = 1; o < 256; o <<= 1) {
        int t = (tid >= o) ? ps[tid - o] : 0;
        __syncthreads();
        ps[tid] += t;
        __syncthreads();
    }
    const int e0 = ps[tid] - (a + b);
    const int e1 = e0 + a;
    const int v0 = bin * 512 + 2 * tid;
    if (v0 < n) rowptr[v0] = b0 + e0;
    if (v0 + 1 < n) rowptr[v0 + 1] = b0 + e1;
    cur[2 * tid] = b0 + e0;
    cur[2 * tid + 1] = b0 + e1;
    __syncthreads();
    for (int e = b0 + tid; e < b1; e += 256) {
        const unsigned v = spack[e];
        const int pos = atomicAdd(&cur[v & 511u], 1);
        csr[pos] = (int)(v >> 9);
    }
}

// ---------------- all-weights transpose+convert (pre-swizzled LDS image) ----------------
// wt layout (mat m): 0 = Wn; layer l: 1+3l = WQ[l], 2+3l = WK[l], 3+3l = WV[l];
// 13+l = WO[l]; 17 = Wout.
// Image holds W^T rows (c-major) with T2 XOR swizzle applied: short-index
// (c*128+k) ^ ((c&7)<<3), so a LINEAR global_load_lds copy lands bank-conflict-free
// for the ds_read_b128 pattern (read side applies the same XOR). [m201/m173 pattern]
struct WPtrs { const float* p[6]; };

__global__ void wtrans_all(WPtrs ws, unsigned short* __restrict__ dst) {
    int i = blockIdx.x * 256 + threadIdx.x;  // over 18*16384
    if (i >= 18 * 16384) return;
    int m = i >> 14;
    int r = i & 16383;
    int k = r >> 7, c = r & 127;  // source element W[k][c]
    const float* s;
    int off;
    if (m == 0)      { s = ws.p[0]; off = 0; }
    else if (m < 13) { int q = (m - 1) % 3, l = (m - 1) / 3; s = ws.p[1 + q]; off = l; }
    else if (m < 17) { s = ws.p[4]; off = m - 13; }
    else             { s = ws.p[5]; off = 0; }
    const int idx = ((c << 7) + k) ^ ((c & 7) << 3);  // swizzled position in 16K-short image
    dst[(size_t)m * 16384 + idx] = f2bf(s[(size_t)off * 16384 + r]);
}

// ---------------- MFMA linear: DMA weight staging + swizzled LDS reads ----------------
// Block = 256 threads = 4 waves, 64 rows; wave w owns rows [blk*64 + w*16, +16).
// wl is LINEAR [128][128] shorts (32 KB); B-read index = (row*128+k) ^ ((row&7)<<3).
__device__ __forceinline__ void stage_w_async(const unsigned short* __restrict__ Wt,
                                              unsigned short* __restrict__ wl,
                                              int w, int lane) {
#pragma unroll
    for (int s = 0; s < 8; ++s) {
        const int off = s * 2048 + w * 512;  // shorts; wave-uniform
        __builtin_amdgcn_global_load_lds(
            (const __attribute__((address_space(1))) void*)(Wt + off + lane * 8),
            (__attribute__((address_space(3))) void*)(wl + off), 16, 0, 0);
    }
}

__device__ __forceinline__ bf16x8 read_w(const unsigned short* __restrict__ wl,
                                         int row, int k) {
    return *(const bf16x8*)&wl[(((row) << 7) + k) ^ ((row & 7) << 3)];
}

__device__ __forceinline__ bf16x8 load_a_bf(const unsigned short* Xb, int row, int k, int n) {
    bf16x8 a = (bf16x8){0, 0, 0, 0, 0, 0, 0, 0};
    if (row < n) a = *(const bf16x8*)&Xb[(size_t)row * HD + k];
    return a;
}
__device__ __forceinline__ bf16x8 load_a_f32(const float* Xf, int row, int k, int n) {
    bf16x8 a = (bf16x8){0, 0, 0, 0, 0, 0, 0, 0};
    if (row < n) {
        float4 x0 = *(const float4*)&Xf[(size_t)row * HD + k];
        float4 x1 = *(const float4*)&Xf[(size_t)row * HD + k + 4];
        a[0] = (short)f2bf(x0.x); a[1] = (short)f2bf(x0.y);
        a[2] = (short)f2bf(x0.z); a[3] = (short)f2bf(x0.w);
        a[4] = (short)f2bf(x1.x); a[5] = (short)f2bf(x1.y);
        a[6] = (short)f2bf(x1.z); a[7] = (short)f2bf(x1.w);
    }
    return a;
}

template <bool AIN_F32, bool RESID_LN, bool OUT_F32, bool OUT_BF>
__global__ __launch_bounds__(256) void lin_lds(
    const void* __restrict__ Xin, const unsigned short* __restrict__ Wt,
    const float* __restrict__ bias,
    const float* __restrict__ lng, const float* __restrict__ lnb,
    const unsigned short* __restrict__ Rb, float* __restrict__ Yf,
    unsigned short* __restrict__ Yb, int n) {
    __shared__ unsigned short wl[128 * 128];
    const int tid = threadIdx.x;
    const int w = tid >> 6;
    const int lane = tid & 63;
    const int t = lane & 15, g = lane >> 4;
    const int waveBase = blockIdx.x * 64 + w * 16;
    const int arow = waveBase + t;

    stage_w_async(Wt, wl, w, lane);

    bf16x8 af[4];
#pragma unroll
    for (int ks = 0; ks < 4; ++ks) {
        const int k = ks * 32 + g * 8;
        af[ks] = AIN_F32 ? load_a_f32((const float*)Xin, arow, k, n)
                         : load_a_bf((const unsigned short*)Xin, arow, k, n);
    }

    __syncthreads();  // drains DMA (vmcnt) -> wl ready

    f32x4 acc[8];
#pragma unroll
    for (int nf = 0; nf < 8; ++nf) acc[nf] = (f32x4){0.f, 0.f, 0.f, 0.f};
#pragma unroll
    for (int ks = 0; ks < 4; ++ks) {
        const int k = ks * 32 + g * 8;
#pragma unroll
        for (int nf = 0; nf < 8; ++nf) {
            bf16x8 b = read_w(wl, nf * 16 + t, k);
            acc[nf] = __builtin_amdgcn_mfma_f32_16x16x32_bf16(af[ks], b, acc[nf], 0, 0, 0);
        }
    }

    float v[8][4];
#pragma unroll
    for (int nf = 0; nf < 8; ++nf) {
        const int col = nf * 16 + t;
        const float bv = bias[col];
#pragma unroll
        for (int r = 0; r < 4; ++r) {
            float x = acc[nf][r] + bv;
            if (RESID_LN) {
                const int row = waveBase + g * 4 + r;
                if (row < n) x += bf2f(Rb[(size_t)row * HD + col]);
            }
            v[nf][r] = x;
        }
    }

    if (RESID_LN) {
#pragma unroll
        for (int r = 0; r < 4; ++r) {
            float s = 0.f, sq = 0.f;
#pragma unroll
            for (int nf = 0; nf < 8; ++nf) { s += v[nf][r]; sq += v[nf][r] * v[nf][r]; }
#pragma unroll
            for (int mask = 1; mask < 16; mask <<= 1) {
                s += __shfl_xor(s, mask, 64);
                sq += __shfl_xor(sq, mask, 64);
            }
            const float mu = s * (1.f / 128.f);
            const float var = sq * (1.f / 128.f) - mu * mu;
            const float inv = rsqrtf(var + 1e-5f);
#pragma unroll
            for (int nf = 0; nf < 8; ++nf) {
                const int col = nf * 16 + t;
                v[nf][r] = (v[nf][r] - mu) * inv * lng[col] + lnb[col];
            }
        }
    }

#pragma unroll
    for (int r = 0; r < 4; ++r) {
        const int row = waveBase + g * 4 + r;
        if (row < n) {
#pragma unroll
            for (int nf = 0; nf < 8; ++nf) {
                const int col = nf * 16 + t;
                if (OUT_F32) Yf[(size_t)row * HD + col] = v[nf][r];
                if (OUT_BF) Yb[(size_t)row * HD + col] = f2bf(v[nf][r]);
            }
        }
    }
}

// ---------------- fused QKV (DMA-staged, 3 consecutive matrices) ----------------
// mat0 -> Q bf16 [n][128]; mat1 -> K into KV[row][0..127]; mat2 -> V into KV[row][128..255]
__global__ __launch_bounds__(256) void lin3_lds(
    const unsigned short* __restrict__ Xb, const unsigned short* __restrict__ Wt3,
    const float* __restrict__ b0, const float* __restrict__ b1, const float* __restrict__ b2,
    unsigned short* __restrict__ Qb, unsigned short* __restrict__ KV, int n) {
    __shared__ unsigned short wl[128 * 128];
    const int tid = threadIdx.x;
    const int w = tid >> 6;
    const int lane = tid & 63;
    const int t = lane & 15, g = lane >> 4;
    const int waveBase = blockIdx.x * 64 + w * 16;
    const int arow = waveBase + t;

    stage_w_async(Wt3, wl, w, lane);

    bf16x8 af[4];
#pragma unroll
    for (int ks = 0; ks < 4; ++ks)
        af[ks] = load_a_bf(Xb, arow, ks * 32 + g * 8, n);

    const float* bs[3] = {b0, b1, b2};

#pragma unroll
    for (int mat = 0; mat < 3; ++mat) {
        __syncthreads();  // mat0: DMA drained; mat>0: prior wl reads done + DMA drained

        f32x4 acc[8];
#pragma unroll
        for (int nf = 0; nf < 8; ++nf) acc[nf] = (f32x4){0.f, 0.f, 0.f, 0.f};
#pragma unroll
        for (int ks = 0; ks < 4; ++ks) {
            const int k = ks * 32 + g * 8;
#pragma unroll
            for (int nf = 0; nf < 8; ++nf) {
                bf16x8 b = read_w(wl, nf * 16 + t, k);
                acc[nf] = __builtin_amdgcn_mfma_f32_16x16x32_bf16(af[ks], b, acc[nf], 0, 0, 0);
            }
        }
        if (mat < 2) {
            __syncthreads();  // all wl reads done before DMA overwrite
            stage_w_async(Wt3 + (size_t)(mat + 1) * 16384, wl, w, lane);
        }

        unsigned short* outp = (mat == 0) ? Qb : KV;
        const int rs = (mat == 0) ? 128 : 256;
        const int co = (mat == 2) ? 128 : 0;
        const float* bb = bs[mat];
#pragma unroll
        for (int r = 0; r < 4; ++r) {
            const int row = waveBase + g * 4 + r;
            if (row < n) {
#pragma unroll
                for (int nf = 0; nf < 8; ++nf) {
                    const int col = nf * 16 + t;
                    outp[(size_t)row * rs + co + col] = f2bf(acc[nf][r] + bb[col]);
                }
            }
        }
    }
}

// ---------------- fused edge attention: no-max softmax, bf16 KV, 8-edge ILP ----------------
__global__ __launch_bounds__(256) void attn_kernel(
    const unsigned short* __restrict__ Qb, const unsigned short* __restrict__ KV,
    const int* __restrict__ rowptr, const int* __restrict__ csr,
    unsigned short* __restrict__ Mb, int n) {
    const int d = (blockIdx.x * 256 + threadIdx.x) >> 6;
    if (d >= n) return;
    const int lane = threadIdx.x & 63;
    const int t = lane & 7, g = lane >> 3;
    const int beg = rowptr[d], end = rowptr[d + 1];

    const float scale = 0.08838834764831845f;  // 1/sqrt(128)
    float qv[16];
    {
        u16x8 q0 = *(const u16x8*)&Qb[(size_t)d * HD + t * 16];
        u16x8 q1 = *(const u16x8*)&Qb[(size_t)d * HD + t * 16 + 8];
#pragma unroll
        for (int j = 0; j < 8; ++j) {
            qv[j] = bf2f(q0[j]) * scale;
            qv[8 + j] = bf2f(q1[j]) * scale;
        }
    }
    float ss = 0.f;
    float acc[16];
#pragma unroll
    for (int j = 0; j < 16; ++j) acc[j] = 0.f;

    const int nit = (end - beg + 7) >> 3;
    for (int it = 0; it < nit; ++it) {
        const int idx = beg + it * 8 + g;
        const bool act = idx < end;
        const int s = act ? csr[idx] : 0;
        const unsigned short* kvp = &KV[(size_t)s * 256 + t * 16];
        const u16x8 k0 = *(const u16x8*)kvp;
        const u16x8 k1 = *(const u16x8*)(kvp + 8);
        const u16x8 v0 = *(const u16x8*)(kvp + 128);
        const u16x8 v1 = *(const u16x8*)(kvp + 136);
        float p = 0.f;
#pragma unroll
        for (int j = 0; j < 8; ++j) {
            p = fmaf(bf2f(k0[j]), qv[j], p);
            p = fmaf(bf2f(k1[j]), qv[8 + j], p);
        }
#pragma unroll
        for (int mask = 1; mask < 8; mask <<= 1) p += __shfl_xor(p, mask, 64);
        const float e = act ? __expf(p) : 0.f;  // LN-scale scores: no max-sub needed in fp32
        ss += e;
#pragma unroll
        for (int j = 0; j < 8; ++j) {
            acc[j] = fmaf(e, bf2f(v0[j]), acc[j]);
            acc[8 + j] = fmaf(e, bf2f(v1[j]), acc[8 + j]);
        }
    }

#pragma unroll
    for (int mask = 8; mask <= 32; mask <<= 1) {
        ss += __shfl_xor(ss, mask, 64);
#pragma unroll
        for (int j = 0; j < 16; ++j) acc[j] += __shfl_xor(acc[j], mask, 64);
    }

    const float inv = (end > beg) ? 1.f / ss : 0.f;
    if (g == 0) {
        u16x8 o0, o1;
#pragma unroll
        for (int j = 0; j < 8; ++j) {
            o0[j] = f2bf(acc[j] * inv);
            o1[j] = f2bf(acc[8 + j] * inv);
        }
        *(u16x8*)&Mb[(size_t)d * HD + t * 16] = o0;
        *(u16x8*)&Mb[(size_t)d * HD + t * 16 + 8] = o1;
    }
}

// ---------------- launch ----------------
extern "C" void kernel_launch(void* const* d_in, const int* in_sizes, int n_in,
                              void* d_out, int out_size, void* d_ws, size_t ws_size,
                              hipStream_t stream) {
    const float* x    = (const float*)d_in[0];
    const void*  eix  = d_in[1];
    const float* Wn   = (const float*)d_in[2];
    const float* bn   = (const float*)d_in[3];
    const float* WQ   = (const float*)d_in[4];
    const float* bQ   = (const float*)d_in[5];
    const float* WK   = (const float*)d_in[6];
    const float* bK   = (const float*)d_in[7];
    const float* WV   = (const float*)d_in[8];
    const float* bV   = (const float*)d_in[9];
    const float* WO   = (const float*)d_in[10];
    const float* bO   = (const float*)d_in[11];
    const float* lng  = (const float*)d_in[12];
    const float* lnb  = (const float*)d_in[13];
    const float* Wout = (const float*)d_in[14];
    const float* bout = (const float*)d_in[15];

    const int n = in_sizes[0] / HD;
    const int E = in_sizes[1] / 2;
    const int L = 4;
    const int NBINS = (n + 511) >> 9;

    char* p = (char*)d_ws;
    auto alloc = [&](size_t bytes) -> void* {
        void* r = (void*)p;
        p += (bytes + 255) & ~(size_t)255;
        return r;
    };
    unsigned short* hb = (unsigned short*)alloc((size_t)n * HD * 2);
    unsigned short* qb = (unsigned short*)alloc((size_t)n * HD * 2);
    unsigned short* kv = (unsigned short*)alloc((size_t)n * HD * 4);  // interleaved K|V
    unsigned short* mb = (unsigned short*)alloc((size_t)n * HD * 2);
    unsigned* spack = (unsigned*)alloc((size_t)E * 4);
    int* csr    = (int*)alloc((size_t)E * 4);
    int* rowptr = (int*)alloc((size_t)(n + 1) * 4);
    int* btot   = (int*)alloc(256 * 4);
    int* bbase  = (int*)alloc(257 * 4);
    int* bcur   = (int*)alloc(256 * 4);
    int* flag   = (int*)alloc(256);
    unsigned short* wt = (unsigned short*)alloc(18 * 16384 * 2);

    const int EB = (E + EPB - 1) / EPB;
    const int nw = (n + 3) / 4;      // attn: wave per dst
    const int nl = (n + 63) / 64;    // linear tiles (64 rows)

    detect_kernel<<<1, 256, 0, stream>>>((const unsigned*)eix, flag);
    hipMemsetAsync(btot, 0, 256 * 4, stream);
    p1_count<<<EB, 256, 0, stream>>>(eix, flag, E, btot, NBINS);
    p1_scan<<<1, 256, 0, stream>>>(btot, bbase, bcur, rowptr, NBINS, n, E);
    p1_scatter<<<EB, 256, 0, stream>>>(eix, flag, E, bcur, spack);
    p2_build<<<NBINS, 256, 0, stream>>>(spack, bbase, rowptr, csr, n);

    WPtrs wp;
    wp.p[0] = Wn; wp.p[1] = WQ; wp.p[2] = WK; wp.p[3] = WV; wp.p[4] = WO; wp.p[5] = Wout;
    wtrans_all<<<(18 * 16384 + 255) / 256, 256, 0, stream>>>(wp, wt);

    // hb = bf16(x @ Wn + bn)
    lin_lds<true, false, false, true><<<nl, 256, 0, stream>>>(
        x, wt, bn, nullptr, nullptr, nullptr, nullptr, hb, n);

    for (int l = 0; l < L; ++l) {
        lin3_lds<<<nl, 256, 0, stream>>>(
            hb, wt + (size_t)(1 + 3 * l) * 16384, bQ + l * HD, bK + l * HD, bV + l * HD,
            qb, kv, n);
        attn_kernel<<<nw, 256, 0, stream>>>(qb, kv, rowptr, csr, mb, n);
        // hb = bf16(LN(hb + mb@WO + bO))  (in-place residual: rows wave-private)
        lin_lds<false, true, false, true><<<nl, 256, 0, stream>>>(
            mb, wt + (size_t)(13 + l) * 16384, bO + l * HD, lng + l * HD, lnb + l * HD,
            hb, nullptr, hb, n);
    }
    lin_lds<false, false, true, false><<<nl, 256, 0, stream>>>(
        hb, wt + (size_t)17 * 16384, bout, nullptr, nullptr, nullptr, (float*)d_out, nullptr, n);
}